// Round 9
// baseline (67.776 us; speedup 1.0000x reference)
//
#include <hip/hip_runtime.h>
#include <hip/hip_bf16.h>

// Problem constants (match reference setup_inputs)
#define BB 64
#define SS 512
#define DD 1024
#define VV 64
#define NSEG (BB * SS)        // 32768

typedef float f32x4 __attribute__((ext_vector_type(4)));
typedef short bf16x8 __attribute__((ext_vector_type(8)));

__device__ __forceinline__ ushort f32_to_bf16_rne(float f) {
    unsigned int b = __float_as_uint(f);
    unsigned int r = b + 0x7fffu + ((b >> 16) & 1u);   // round-to-nearest-even
    return (ushort)(r >> 16);
}

// ---------- Pass A: segment start offsets from sorted segment_ids ----------
__global__ __launch_bounds__(256) void fill_bounds_kernel(
    const int* __restrict__ seg_ids,
    int* __restrict__ seg_start,
    int T)
{
    int t = blockIdx.x * blockDim.x + threadIdx.x;
    if (t >= T) return;
    int cur  = seg_ids[t];
    int prev = (t == 0) ? -1 : seg_ids[t - 1];
    for (int s = prev + 1; s <= cur; ++s) seg_start[s] = t;
    if (t == T - 1) {
        for (int s = cur + 1; s <= NSEG; ++s) seg_start[s] = T;
    }
}

// ---------- Pass B: build H histogram [NSEG][VV] f32 (counts; no atomics) ----------
__global__ __launch_bounds__(256) void build_h_kernel(
    const int* __restrict__ tokens,
    const int* __restrict__ seg_start,
    float* __restrict__ H)
{
    __shared__ float h[256 * VV];                    // 64 KB
    const int tid  = threadIdx.x;
    const int seg0 = blockIdx.x * 256;
    for (int i = tid; i < 256 * VV; i += 256) h[i] = 0.f;
    __syncthreads();
    const int seg = seg0 + tid;                      // row owned by this thread
    const int lo = seg_start[seg];
    const int hi = seg_start[seg + 1];
    for (int t = lo; t < hi; ++t) h[tid * VV + tokens[t]] += 1.f;
    __syncthreads();
    const f32x4* src = (const f32x4*)h;
    f32x4* dst = (f32x4*)(H + (size_t)seg0 * VV);
    for (int i = tid; i < 256 * VV / 4; i += 256) dst[i] = src[i];
}

// ---------- Pass C: swizzle emb -> A-fragment layout (bf16) ----------
// A = E^T tile fragments for mfma_f32_16x16x32_bf16:
// A_swz[((mt*2+ks)*64 + lane)*8 + j] = bf16(emb[(ks*32 + (lane>>4)*8 + j)*DD + mt*16 + (lane&15)])
__global__ __launch_bounds__(256) void swz_emb_kernel(
    const float* __restrict__ emb,
    ushort* __restrict__ A)
{
    const int g    = blockIdx.x * 256 + threadIdx.x;  // 0..8191 (32 blocks x 256)
    const int lane = g & 63;
    const int tile = g >> 6;                          // mt*2 + ks, 0..127
    const int ks   = tile & 1;
    const int mt   = tile >> 1;
    const int dim  = mt * 16 + (lane & 15);
    const int v0   = ks * 32 + (lane >> 4) * 8;
    bf16x8 w;
    #pragma unroll
    for (int j = 0; j < 8; ++j)
        w[j] = (short)f32_to_bf16_rne(emb[(size_t)(v0 + j) * DD + dim]);
    *reinterpret_cast<bf16x8*>(A + (size_t)g * 8) = w;
}

// ---------- Pass D: MFMA GEMM  out[seg][dim] = inv_cnt * (E^T · H^T)[dim][seg] + pos ----------
// Swapped product: D-tile [dim][seg] so each lane's 4 acc values = 4 consecutive dims
// of ONE segment -> 16B dwordx4 store; 4 lane-groups give 64B contiguous per seg row.
#define MW 64   // dims per wave (4 m-frags)
#define NW 32   // segs per wave (2 n-frags)
__global__ __launch_bounds__(256) void gemm_kernel(
    const ushort* __restrict__ A,       // swizzled emb fragments
    const float* __restrict__ H,        // [NSEG][VV] counts (f32, small ints)
    const int* __restrict__ seg_start,  // [NSEG+1]
    const float* __restrict__ pos,      // [S, D]
    float* __restrict__ out)            // [B*S, D]
{
    const int warp = threadIdx.x >> 6;
    const int lane = threadIdx.x & 63;
    const int mgrp = blockIdx.x & 15;               // 1024/MW = 16
    const int ngrp = blockIdx.x >> 4;               // 32768/(NW*4) = 256
    const int m_base = mgrp * MW;
    const int n_base = ngrp * (NW * 4) + warp * NW;

    // A fragments: row(dim) = lane&15, k(v) = (lane>>4)*8+j  (pre-swizzled, 16B loads)
    const int mt0 = m_base >> 4;
    bf16x8 a[4][2];
    #pragma unroll
    for (int mi = 0; mi < 4; ++mi)
        #pragma unroll
        for (int ks = 0; ks < 2; ++ks)
            a[mi][ks] = *reinterpret_cast<const bf16x8*>(
                A + ((size_t)((mt0 + mi) * 2 + ks) * 64 + lane) * 8);

    // B fragments: col(seg) = lane&15, k(v) = (lane>>4)*8+j.
    // H counts are small integers: bf16 truncation (>>16) is exact.
    bf16x8 b[2][2];
    #pragma unroll
    for (int ni = 0; ni < 2; ++ni) {
        const int seg = n_base + ni * 16 + (lane & 15);
        const float* hrow = H + (size_t)seg * VV + (lane >> 4) * 8;
        #pragma unroll
        for (int ks = 0; ks < 2; ++ks) {
            const f32x4 h0 = *reinterpret_cast<const f32x4*>(hrow + ks * 32);
            const f32x4 h1 = *reinterpret_cast<const f32x4*>(hrow + ks * 32 + 4);
            bf16x8 w;
            w[0] = (short)(__float_as_uint(h0[0]) >> 16);
            w[1] = (short)(__float_as_uint(h0[1]) >> 16);
            w[2] = (short)(__float_as_uint(h0[2]) >> 16);
            w[3] = (short)(__float_as_uint(h0[3]) >> 16);
            w[4] = (short)(__float_as_uint(h1[0]) >> 16);
            w[5] = (short)(__float_as_uint(h1[1]) >> 16);
            w[6] = (short)(__float_as_uint(h1[2]) >> 16);
            w[7] = (short)(__float_as_uint(h1[3]) >> 16);
            b[ni][ks] = w;
        }
    }

    f32x4 acc[4][2];
    #pragma unroll
    for (int mi = 0; mi < 4; ++mi)
        #pragma unroll
        for (int ni = 0; ni < 2; ++ni)
            acc[mi][ni] = (f32x4)(0.f);

    #pragma unroll
    for (int ks = 0; ks < 2; ++ks)
        #pragma unroll
        for (int mi = 0; mi < 4; ++mi)
            #pragma unroll
            for (int ni = 0; ni < 2; ++ni)
                acc[mi][ni] = __builtin_amdgcn_mfma_f32_16x16x32_bf16(
                    a[mi][ks], b[ni][ks], acc[mi][ni], 0, 0, 0);

    // Epilogue: scale by 1/cnt, add pos, NT store (16B per lane per frag)
    float inv[2];
    #pragma unroll
    for (int ni = 0; ni < 2; ++ni) {
        const int seg = n_base + ni * 16 + (lane & 15);
        const int cnt = seg_start[seg + 1] - seg_start[seg];
        inv[ni] = (cnt > 0) ? (1.0f / (float)cnt) : 0.0f;
    }
    const int dimq = (lane >> 4) * 4;               // C/D row = (lane>>4)*4 + j
    #pragma unroll
    for (int ni = 0; ni < 2; ++ni) {
        const int seg  = n_base + ni * 16 + (lane & 15);
        const int srow = seg & (SS - 1);
        #pragma unroll
        for (int mi = 0; mi < 4; ++mi) {
            const int dim = m_base + mi * 16 + dimq;
            const f32x4 p = *reinterpret_cast<const f32x4*>(
                pos + (size_t)srow * DD + dim);
            f32x4 o = acc[mi][ni] * inv[ni] + p;
            __builtin_nontemporal_store(o,
                reinterpret_cast<f32x4*>(out + (size_t)seg * DD + dim));
        }
    }
}

// ---------- Fallback (ws too small): R3-style gather ----------
__device__ __forceinline__ int lower_bound_dev(const int* __restrict__ a, int n, int key) {
    int lo = 0, hi = n;
    while (lo < hi) {
        int mid = (lo + hi) >> 1;
        if (a[mid] < key) lo = mid + 1; else hi = mid;
    }
    return lo;
}

__global__ __launch_bounds__(256) void seg_mean_embed_bsearch_kernel(
    const int* __restrict__ tokens,
    const int* __restrict__ seg_ids,
    const float* __restrict__ emb,
    const float* __restrict__ pos,
    float* __restrict__ out,
    int T)
{
    const int seg = blockIdx.x;
    const int lo = lower_bound_dev(seg_ids, T, seg);
    const int hi = lower_bound_dev(seg_ids, T, seg + 1);
    const int d = threadIdx.x * 4;

    f32x4 acc = (f32x4)(0.f);
    for (int t = lo; t < hi; ++t) {
        const int tok = tokens[t];
        acc += *reinterpret_cast<const f32x4*>(emb + (size_t)tok * DD + d);
    }
    const int cnt = hi - lo;
    const float inv = (cnt > 0) ? (1.0f / (float)cnt) : 0.0f;
    const int s = seg & (SS - 1);
    const f32x4 p = *reinterpret_cast<const f32x4*>(pos + (size_t)s * DD + d);
    f32x4 o = acc * inv + p;
    *reinterpret_cast<f32x4*>(out + (size_t)seg * DD + d) = o;
}

extern "C" void kernel_launch(void* const* d_in, const int* in_sizes, int n_in,
                              void* d_out, int out_size, void* d_ws, size_t ws_size,
                              hipStream_t stream) {
    const int*   tokens  = (const int*)d_in[0];
    const int*   seg_ids = (const int*)d_in[1];
    const float* emb     = (const float*)d_in[2];
    const float* pos     = (const float*)d_in[3];
    float*       out     = (float*)d_out;
    const int T = in_sizes[0];

    // ws layout: A_swz [0,128KB) | H [128KB, 128KB+8MB) | seg_start after
    const size_t a_bytes  = (size_t)128 * 64 * 8 * sizeof(ushort);     // 131072
    const size_t h_bytes  = (size_t)NSEG * VV * sizeof(float);         // 8388608
    const size_t need = a_bytes + h_bytes + (size_t)(NSEG + 1) * sizeof(int);

    if (ws_size >= need) {
        ushort* A         = (ushort*)d_ws;
        float*  H         = (float*)((char*)d_ws + a_bytes);
        int*    seg_start = (int*)((char*)d_ws + a_bytes + h_bytes);

        fill_bounds_kernel<<<(T + 255) / 256, 256, 0, stream>>>(seg_ids, seg_start, T);
        build_h_kernel<<<NSEG / 256, 256, 0, stream>>>(tokens, seg_start, H);
        swz_emb_kernel<<<32, 256, 0, stream>>>(emb, A);
        gemm_kernel<<<4096, 256, 0, stream>>>(A, H, seg_start, pos, out);
    } else {
        seg_mean_embed_bsearch_kernel<<<NSEG, 256, 0, stream>>>(tokens, seg_ids, emb, pos, out, T);
    }
}

// Round 10
// 40.258 us; speedup vs baseline: 1.6835x; 1.6835x over previous
//
#include <hip/hip_runtime.h>
#include <hip/hip_bf16.h>

// Problem constants (match reference setup_inputs)
#define BB 64
#define SS 512
#define DD 1024
#define VV 64
#define NSEG (BB * SS)        // 32768
#define THREADS 512
#define WPB (THREADS / 64)    // 8 waves per block, one segment per wave
#define GRID (NSEG / WPB)     // 4096 blocks

typedef float f32x4 __attribute__((ext_vector_type(4)));

// ---------- Pass A: segment start offsets from sorted segment_ids ----------
__global__ __launch_bounds__(256) void fill_bounds_kernel(
    const int* __restrict__ seg_ids,
    int* __restrict__ seg_start,
    int T)
{
    int t = blockIdx.x * blockDim.x + threadIdx.x;
    if (t >= T) return;
    int cur  = seg_ids[t];
    int prev = (t == 0) ? -1 : seg_ids[t - 1];
    for (int s = prev + 1; s <= cur; ++s) seg_start[s] = t;
    if (t == T - 1) {
        for (int s = cur + 1; s <= NSEG; ++s) seg_start[s] = T;
    }
}

// ---------- Pass B: wave-per-segment gather ----------
// Each 64-lane wave owns one whole segment row (D=1024): lane covers 4x f32x4
// chunks at d = k*256 + lane*4. Per wave: 4 independent 1KB coalesced stores,
// one seg_start/tokens chain amortized over 4KB of output, no barriers,
// 8x fewer workgroups than R3 (4096 x 512thr).
__global__ __launch_bounds__(THREADS) void seg_mean_wps_kernel(
    const int* __restrict__ tokens,
    const int* __restrict__ seg_start,  // [NSEG+1]
    const float* __restrict__ emb,      // [V, D]
    const float* __restrict__ pos,      // [S, D]
    float* __restrict__ out)            // [B*S, D]
{
    const int wave = threadIdx.x >> 6;
    const int lane = threadIdx.x & 63;
    const int seg  = blockIdx.x * WPB + wave;
    const int d0   = lane * 4;

    const int lo = seg_start[seg];
    const int hi = seg_start[seg + 1];

    // pos loads are independent of the gather chain -> issue first
    const float* prow = pos + (size_t)(seg & (SS - 1)) * DD + d0;
    f32x4 p0 = *reinterpret_cast<const f32x4*>(prow);
    f32x4 p1 = *reinterpret_cast<const f32x4*>(prow + 256);
    f32x4 p2 = *reinterpret_cast<const f32x4*>(prow + 512);
    f32x4 p3 = *reinterpret_cast<const f32x4*>(prow + 768);

    f32x4 a0 = (f32x4)(0.f), a1 = (f32x4)(0.f), a2 = (f32x4)(0.f), a3 = (f32x4)(0.f);
    for (int t = lo; t < hi; ++t) {
        const int tok = tokens[t];               // uniform across wave
        const float* erow = emb + (size_t)tok * DD + d0;
        a0 += *reinterpret_cast<const f32x4*>(erow);
        a1 += *reinterpret_cast<const f32x4*>(erow + 256);
        a2 += *reinterpret_cast<const f32x4*>(erow + 512);
        a3 += *reinterpret_cast<const f32x4*>(erow + 768);
    }

    const int cnt = hi - lo;
    const float inv = (cnt > 0) ? (1.0f / (float)cnt) : 0.0f;

    f32x4 o0 = a0 * inv + p0;
    f32x4 o1 = a1 * inv + p1;
    f32x4 o2 = a2 * inv + p2;
    f32x4 o3 = a3 * inv + p3;

    float* orow = out + (size_t)seg * DD + d0;
    __builtin_nontemporal_store(o0, reinterpret_cast<f32x4*>(orow));
    __builtin_nontemporal_store(o1, reinterpret_cast<f32x4*>(orow + 256));
    __builtin_nontemporal_store(o2, reinterpret_cast<f32x4*>(orow + 512));
    __builtin_nontemporal_store(o3, reinterpret_cast<f32x4*>(orow + 768));
}

// ---------- Fallback (ws too small): binary-search kernel ----------
__device__ __forceinline__ int lower_bound_dev(const int* __restrict__ a, int n, int key) {
    int lo = 0, hi = n;
    while (lo < hi) {
        int mid = (lo + hi) >> 1;
        if (a[mid] < key) lo = mid + 1; else hi = mid;
    }
    return lo;
}

__global__ __launch_bounds__(256) void seg_mean_embed_bsearch_kernel(
    const int* __restrict__ tokens,
    const int* __restrict__ seg_ids,
    const float* __restrict__ emb,
    const float* __restrict__ pos,
    float* __restrict__ out,
    int T)
{
    const int seg = blockIdx.x;
    const int lo = lower_bound_dev(seg_ids, T, seg);
    const int hi = lower_bound_dev(seg_ids, T, seg + 1);
    const int d = threadIdx.x * 4;

    f32x4 acc = (f32x4)(0.f);
    for (int t = lo; t < hi; ++t) {
        const int tok = tokens[t];
        acc += *reinterpret_cast<const f32x4*>(emb + (size_t)tok * DD + d);
    }
    const int cnt = hi - lo;
    const float inv = (cnt > 0) ? (1.0f / (float)cnt) : 0.0f;
    const int s = seg & (SS - 1);
    const f32x4 p = *reinterpret_cast<const f32x4*>(pos + (size_t)s * DD + d);
    f32x4 o = acc * inv + p;
    *reinterpret_cast<f32x4*>(out + (size_t)seg * DD + d) = o;
}

extern "C" void kernel_launch(void* const* d_in, const int* in_sizes, int n_in,
                              void* d_out, int out_size, void* d_ws, size_t ws_size,
                              hipStream_t stream) {
    const int*   tokens  = (const int*)d_in[0];
    const int*   seg_ids = (const int*)d_in[1];
    const float* emb     = (const float*)d_in[2];
    const float* pos     = (const float*)d_in[3];
    float*       out     = (float*)d_out;
    const int T = in_sizes[0];

    const size_t need = (size_t)(NSEG + 1) * sizeof(int);
    if (ws_size >= need) {
        int* seg_start = (int*)d_ws;
        fill_bounds_kernel<<<(T + 255) / 256, 256, 0, stream>>>(seg_ids, seg_start, T);
        seg_mean_wps_kernel<<<GRID, THREADS, 0, stream>>>(tokens, seg_start, emb, pos, out);
    } else {
        seg_mean_embed_bsearch_kernel<<<NSEG, 256, 0, stream>>>(tokens, seg_ids, emb, pos, out, T);
    }
}